// Round 2
// baseline (591.997 us; speedup 1.0000x reference)
//
#include <hip/hip_runtime.h>
#include <stdint.h>

typedef __attribute__((ext_vector_type(4))) float f32x4;
typedef __attribute__((ext_vector_type(8))) short short8;

#define MM 16
#define BB 2048
#define UU 16
#define ZD 64
#define HH 512
#define XD 3072
#define RTOT (MM * BB)  // 32768

#define MFMA16(a, b, c) __builtin_amdgcn_mfma_f32_16x16x32_bf16(a, b, c, 0, 0, 0)

static __device__ __forceinline__ unsigned short f2bf(float f) {
  union { float f; uint32_t u; } v; v.f = f;
  uint32_t r = v.u + 0x7fffu + ((v.u >> 16) & 1u);
  return (unsigned short)(r >> 16);
}

static __device__ __forceinline__ void async16(const void* g, void* l) {
  __builtin_amdgcn_global_load_lds(
      (const __attribute__((address_space(1))) uint32_t*)g,
      (__attribute__((address_space(3))) uint32_t*)l, 16, 0, 0);
}

// ---------------- K0: transpose + fp32->bf16 convert, all 4 weights ----------------
// in: (bat, R, C) fp32 row-major  ->  out: (bat, C, R) bf16 row-major
static __device__ __forceinline__ void tr_tile(const float* __restrict__ in,
                                               unsigned short* __restrict__ out,
                                               int R, int C, int c0, int r0, int z,
                                               float (*tile)[33]) {
  const size_t base = (size_t)z * R * C;
  const int tx = threadIdx.x & 31, ty = threadIdx.x >> 5;  // 32x8
#pragma unroll
  for (int k = 0; k < 32; k += 8)
    tile[ty + k][tx] = in[base + (size_t)(r0 + ty + k) * C + c0 + tx];
  __syncthreads();
#pragma unroll
  for (int k = 0; k < 32; k += 8)
    out[base + (size_t)(c0 + ty + k) * R + r0 + tx] = f2bf(tile[tx][ty + k]);
}

// block ranges: [0,64) Wzz | [64,576) Wzh | [576,832) Whd | [832,2368) Whx
__global__ __launch_bounds__(256) void trconv_all(
    const float* __restrict__ Wzz, const float* __restrict__ Wzh,
    const float* __restrict__ Whd, const float* __restrict__ Whx,
    unsigned short* __restrict__ wzzT, unsigned short* __restrict__ wzhT,
    unsigned short* __restrict__ whdT, unsigned short* __restrict__ whxT) {
  __shared__ float tile[32][33];
  int b = blockIdx.x;
  if (b < 64) {  // Wzz: R=64 C=64 bat=16, cx=2 ry=2
    int l = b;
    tr_tile(Wzz, wzzT, 64, 64, (l & 1) * 32, ((l >> 1) & 1) * 32, l >> 2, tile);
  } else if (b < 576) {  // Wzh: R=64 C=512 bat=16, cx=16 ry=2
    int l = b - 64;
    tr_tile(Wzh, wzhT, 64, 512, (l & 15) * 32, ((l >> 4) & 1) * 32, l >> 5, tile);
  } else if (b < 832) {  // Whd: R=512 C=512, cx=16 ry=16
    int l = b - 576;
    tr_tile(Whd, whdT, 512, 512, (l & 15) * 32, (l >> 4) * 32, 0, tile);
  } else {  // Whx: R=512 C=3072, cx=96 ry=16
    int l = b - 832;
    tr_tile(Whx, whxT, 512, 3072, (l % 96) * 32, (l / 96) * 32, 0, tile);
  }
}

// ---------------- K1: fused stage1+2 per m ----------------
// z = s[m, rows, 16:80]; zz = z@Wzz + bzz; h1 = relu(zz@Wzh + bzh)
__global__ __launch_bounds__(256) void stage12(
    const float* __restrict__ s, const unsigned short* __restrict__ wzzT,
    const unsigned short* __restrict__ wzhT, const float* __restrict__ bzz,
    const float* __restrict__ bzh, unsigned short* __restrict__ h1) {
  __shared__ __align__(16) unsigned short zA[128 * 64];       // 16KB, reused as zz
  __shared__ __align__(16) unsigned short wzz[64 * 64];       // 8KB
  __shared__ __align__(16) unsigned short wbuf[2][128 * 64];  // 32KB
  const int m = blockIdx.y;
  const int m0r = blockIdx.x * 128;
  const int t = threadIdx.x, lane = t & 63, w = t >> 6;
  const int l15 = lane & 15, l4 = lane >> 4;

  // async weight stages first (overlap with z conversion)
  {
    const unsigned short* g = wzzT + (size_t)m * 64 * 64;
    async16(g + t * 8, &wzz[t * 8]);
    async16(g + (t + 256) * 8, &wzz[(t + 256) * 8]);
    const unsigned short* gh = wzhT + (size_t)m * 512 * 64;  // chunk0: rows 0..127
#pragma unroll
    for (int it = 0; it < 4; ++it) {
      int id = it * 256 + t;
      async16(gh + id * 8, &wbuf[0][id * 8]);
    }
  }
  // z load + convert: 128 rows x 64 (s row stride = 80 floats, z at +16)
  const float* sb = s + ((size_t)m * BB + m0r) * (UU + ZD) + UU;
#pragma unroll
  for (int it = 0; it < 8; ++it) {
    int idx = it * 256 + t;  // 0..2047
    int row = idx >> 4, f4 = idx & 15;
    const float4 v = *(const float4*)(sb + (size_t)row * (UU + ZD) + f4 * 4);
    ushort4 h;
    h.x = f2bf(v.x); h.y = f2bf(v.y); h.z = f2bf(v.z); h.w = f2bf(v.w);
    *(ushort4*)&zA[row * 64 + f4 * 4] = h;
  }
  __syncthreads();

  // stage1: zz = z @ Wzz  (A: zA [128][64], B: wzzT [64cols][64k])
  f32x4 acc1[2][4] = {};
#pragma unroll
  for (int ks = 0; ks < 2; ++ks) {
    short8 af[2], bf[4];
#pragma unroll
    for (int i = 0; i < 2; ++i)
      af[i] = *(const short8*)&zA[(w * 32 + i * 16 + l15) * 64 + ks * 32 + l4 * 8];
#pragma unroll
    for (int n = 0; n < 4; ++n)
      bf[n] = *(const short8*)&wzz[(n * 16 + l15) * 64 + ks * 32 + l4 * 8];
#pragma unroll
    for (int i = 0; i < 2; ++i)
#pragma unroll
      for (int n = 0; n < 4; ++n) acc1[i][n] = MFMA16(af[i], bf[n], acc1[i][n]);
  }
  // issue wzh chunk1 while stage1 finishes
  {
    const unsigned short* gh = wzhT + (size_t)m * 512 * 64 + 128 * 64;
#pragma unroll
    for (int it = 0; it < 4; ++it) {
      int id = it * 256 + t;
      async16(gh + id * 8, &wbuf[1][id * 8]);
    }
  }
  __syncthreads();  // all zA reads done -> safe to overwrite with zz
  unsigned short* zzp = zA;
#pragma unroll
  for (int i = 0; i < 2; ++i)
#pragma unroll
    for (int n = 0; n < 4; ++n)
#pragma unroll
      for (int r = 0; r < 4; ++r) {
        int row = w * 32 + i * 16 + l4 * 4 + r;
        int col = n * 16 + l15;
        zzp[row * 64 + col] = f2bf(acc1[i][n][r] + bzz[m * 64 + col]);
      }
  __syncthreads();  // zz ready; chunk1 drained too

  // stage2: h1 = relu(zz @ Wzh + bzh), 512 cols in 4 chunks of 128
  unsigned short* h1r = h1 + ((size_t)m * BB + m0r) * HH;
  for (int c = 0; c < 4; ++c) {
    f32x4 acc[2][8] = {};
#pragma unroll
    for (int ks = 0; ks < 2; ++ks) {
      short8 af[2], bf[8];
#pragma unroll
      for (int i = 0; i < 2; ++i)
        af[i] = *(const short8*)&zzp[(w * 32 + i * 16 + l15) * 64 + ks * 32 + l4 * 8];
#pragma unroll
      for (int n = 0; n < 8; ++n)
        bf[n] = *(const short8*)&wbuf[c & 1][(n * 16 + l15) * 64 + ks * 32 + l4 * 8];
#pragma unroll
      for (int i = 0; i < 2; ++i)
#pragma unroll
        for (int n = 0; n < 8; ++n) acc[i][n] = MFMA16(af[i], bf[n], acc[i][n]);
    }
#pragma unroll
    for (int i = 0; i < 2; ++i)
#pragma unroll
      for (int n = 0; n < 8; ++n)
#pragma unroll
        for (int r = 0; r < 4; ++r) {
          int row = w * 32 + i * 16 + l4 * 4 + r;
          int col = c * 128 + n * 16 + l15;
          float v = acc[i][n][r] + bzh[m * HH + col];
          h1r[(size_t)row * HH + col] = f2bf(fmaxf(v, 0.0f));
        }
    __syncthreads();  // everyone done reading wbuf[c&1]
    if (c + 2 < 4) {
      const unsigned short* gh = wzhT + (size_t)m * 512 * 64 + (size_t)(c + 2) * 128 * 64;
#pragma unroll
      for (int it = 0; it < 4; ++it) {
        int id = it * 256 + t;
        async16(gh + id * 8, &wbuf[c & 1][id * 8]);
      }
    }
  }
}

// ---------------- K2/K3: 128x128-tile bf16 GEMM, B^T layout ----------------
// EPI 0: relu -> bf16 out.  EPI 1: sigmoid -> f32 out.  Ntot/Ktot compile-time.
template <int EPI, int Ntot, int Ktot>
__global__ __launch_bounds__(256) void gemm_bt(
    const unsigned short* __restrict__ A,   // [Mtot][Ktot] bf16
    const unsigned short* __restrict__ BT,  // [Ntot][Ktot] bf16
    const float* __restrict__ bias,         // [Ntot]
    void* __restrict__ outp) {
  __shared__ __align__(16) unsigned short lA[2][128 * 32];  // 2x8KB
  __shared__ __align__(16) unsigned short lB[2][128 * 32];  // 2x8KB
  const int t = threadIdx.x, lane = t & 63;
  const int wid = t >> 6, wr = wid >> 1, wc = wid & 1;  // 2x2 waves, 64x64 each
  const int l15 = lane & 15, l4 = lane >> 4;
  const int m0 = blockIdx.x * 128, n0 = blockIdx.y * 128;

  const int ra = t >> 2;       // staging row (0..63); +64 for 2nd chunk
  const int sa = (t & 3) * 8;  // k-seg within 32 (elements)

  const unsigned short* gA = A + (size_t)m0 * Ktot;
  const unsigned short* gB = BT + (size_t)n0 * Ktot;

  float bv[4];
#pragma unroll
  for (int n = 0; n < 4; ++n) bv[n] = bias[n0 + wc * 64 + n * 16 + l15];

  f32x4 acc[4][4] = {};
  constexpr int NT = Ktot / 32;

  {  // prologue stage into buf 0
    const unsigned short* a0 = gA + (size_t)ra * Ktot + sa;
    const unsigned short* b0 = gB + (size_t)ra * Ktot + sa;
    async16(a0, &lA[0][t * 8]);
    async16(a0 + (size_t)64 * Ktot, &lA[0][(t + 256) * 8]);
    async16(b0, &lB[0][t * 8]);
    async16(b0 + (size_t)64 * Ktot, &lB[0][(t + 256) * 8]);
  }
  __syncthreads();
  for (int ks = 0; ks < NT; ++ks) {
    const int cur = ks & 1;
    if (ks + 1 < NT) {
      const int ko = (ks + 1) * 32;
      const unsigned short* a0 = gA + (size_t)ra * Ktot + ko + sa;
      const unsigned short* b0 = gB + (size_t)ra * Ktot + ko + sa;
      async16(a0, &lA[cur ^ 1][t * 8]);
      async16(a0 + (size_t)64 * Ktot, &lA[cur ^ 1][(t + 256) * 8]);
      async16(b0, &lB[cur ^ 1][t * 8]);
      async16(b0 + (size_t)64 * Ktot, &lB[cur ^ 1][(t + 256) * 8]);
    }
    short8 af[4], bf[4];
#pragma unroll
    for (int i = 0; i < 4; ++i)
      af[i] = *(const short8*)&lA[cur][(wr * 64 + i * 16 + l15) * 32 + l4 * 8];
#pragma unroll
    for (int n = 0; n < 4; ++n)
      bf[n] = *(const short8*)&lB[cur][(wc * 64 + n * 16 + l15) * 32 + l4 * 8];
#pragma unroll
    for (int i = 0; i < 4; ++i)
#pragma unroll
      for (int n = 0; n < 4; ++n) acc[i][n] = MFMA16(af[i], bf[n], acc[i][n]);
    __syncthreads();
  }

  // epilogue
#pragma unroll
  for (int i = 0; i < 4; ++i)
#pragma unroll
    for (int n = 0; n < 4; ++n) {
      const int col = n0 + wc * 64 + n * 16 + l15;
#pragma unroll
      for (int r = 0; r < 4; ++r) {
        const int row = m0 + wr * 64 + i * 16 + l4 * 4 + r;
        float v = acc[i][n][r] + bv[n];
        if (EPI == 0) {
          ((unsigned short*)outp)[(size_t)row * Ntot + col] = f2bf(fmaxf(v, 0.0f));
        } else {
          v = 1.0f / (1.0f + __expf(-v));
          ((float*)outp)[(size_t)row * Ntot + col] = v;
        }
      }
    }
}

extern "C" void kernel_launch(void* const* d_in, const int* in_sizes, int n_in,
                              void* d_out, int out_size, void* d_ws, size_t ws_size,
                              hipStream_t stream) {
  const float* s   = (const float*)d_in[0];
  const float* Wzz = (const float*)d_in[1];
  const float* bzz = (const float*)d_in[2];
  const float* Wzh = (const float*)d_in[3];
  const float* bzh = (const float*)d_in[4];
  const float* Whd = (const float*)d_in[5];
  const float* bhd = (const float*)d_in[6];
  const float* Whx = (const float*)d_in[7];
  const float* bhx = (const float*)d_in[8];
  float* out = (float*)d_out;

  char* ws = (char*)d_ws;
  unsigned short* wzzT = (unsigned short*)ws; ws += (size_t)MM * 64 * 64 * 2;
  unsigned short* wzhT = (unsigned short*)ws; ws += (size_t)MM * 512 * 64 * 2;
  unsigned short* whdT = (unsigned short*)ws; ws += (size_t)512 * 512 * 2;
  unsigned short* whxT = (unsigned short*)ws; ws += (size_t)3072 * 512 * 2;
  unsigned short* h1   = (unsigned short*)ws; ws += (size_t)RTOT * 512 * 2;
  unsigned short* h2   = (unsigned short*)ws;

  dim3 blk(256);
  trconv_all<<<dim3(2368), blk, 0, stream>>>(Wzz, Wzh, Whd, Whx, wzzT, wzhT, whdT, whxT);
  stage12<<<dim3(16, 16), blk, 0, stream>>>(s, wzzT, wzhT, bzz, bzh, h1);
  gemm_bt<0, HH, HH><<<dim3(256, 4), blk, 0, stream>>>(h1, whdT, bhd, (void*)h2);
  gemm_bt<1, XD, HH><<<dim3(256, 24), blk, 0, stream>>>(h2, whxT, bhx, (void*)out);
}

// Round 9
// 569.365 us; speedup vs baseline: 1.0397x; 1.0397x over previous
//
#include <hip/hip_runtime.h>
#include <stdint.h>

typedef __attribute__((ext_vector_type(4))) float f32x4;
typedef __attribute__((ext_vector_type(8))) short short8;

#define MM 16
#define BB 2048
#define UU 16
#define ZD 64
#define HH 512
#define XD 3072
#define RTOT (MM * BB)  // 32768

#define MFMA16(a, b, c) __builtin_amdgcn_mfma_f32_16x16x32_bf16(a, b, c, 0, 0, 0)

static __device__ __forceinline__ unsigned short f2bf(float f) {
  union { float f; uint32_t u; } v; v.f = f;
  uint32_t r = v.u + 0x7fffu + ((v.u >> 16) & 1u);
  return (unsigned short)(r >> 16);
}

static __device__ __forceinline__ void async16(const void* g, void* l) {
  __builtin_amdgcn_global_load_lds(
      (const __attribute__((address_space(1))) uint32_t*)g,
      (__attribute__((address_space(3))) uint32_t*)l, 16, 0, 0);
}

// ---------------- K0: transpose + fp32->bf16 convert, all 4 weights ----------------
static __device__ __forceinline__ void tr_tile(const float* __restrict__ in,
                                               unsigned short* __restrict__ out,
                                               int R, int C, int c0, int r0, int z,
                                               float (*tile)[33]) {
  const size_t base = (size_t)z * R * C;
  const int tx = threadIdx.x & 31, ty = threadIdx.x >> 5;  // 32x8
#pragma unroll
  for (int k = 0; k < 32; k += 8)
    tile[ty + k][tx] = in[base + (size_t)(r0 + ty + k) * C + c0 + tx];
  __syncthreads();
#pragma unroll
  for (int k = 0; k < 32; k += 8)
    out[base + (size_t)(c0 + ty + k) * R + r0 + tx] = f2bf(tile[tx][ty + k]);
}

// block ranges: [0,64) Wzz | [64,576) Wzh | [576,832) Whd | [832,2368) Whx
__global__ __launch_bounds__(256) void trconv_all(
    const float* __restrict__ Wzz, const float* __restrict__ Wzh,
    const float* __restrict__ Whd, const float* __restrict__ Whx,
    unsigned short* __restrict__ wzzT, unsigned short* __restrict__ wzhT,
    unsigned short* __restrict__ whdT, unsigned short* __restrict__ whxT) {
  __shared__ float tile[32][33];
  int b = blockIdx.x;
  if (b < 64) {
    int l = b;
    tr_tile(Wzz, wzzT, 64, 64, (l & 1) * 32, ((l >> 1) & 1) * 32, l >> 2, tile);
  } else if (b < 576) {
    int l = b - 64;
    tr_tile(Wzh, wzhT, 64, 512, (l & 15) * 32, ((l >> 4) & 1) * 32, l >> 5, tile);
  } else if (b < 832) {
    int l = b - 576;
    tr_tile(Whd, whdT, 512, 512, (l & 15) * 32, (l >> 4) * 32, 0, tile);
  } else {
    int l = b - 832;
    tr_tile(Whx, whxT, 512, 3072, (l % 96) * 32, (l / 96) * 32, 0, tile);
  }
}

// ---------------- K1: fused stage1+2 per m, 64 rows/block (512 blocks, 2/CU) ----------------
__global__ __launch_bounds__(256) void stage12(
    const float* __restrict__ s, const unsigned short* __restrict__ wzzT,
    const unsigned short* __restrict__ wzhT, const float* __restrict__ bzz,
    const float* __restrict__ bzh, unsigned short* __restrict__ h1) {
  __shared__ __align__(16) unsigned short zA[64 * 64];        // 8KB, reused as zz
  __shared__ __align__(16) unsigned short wzz[64 * 64];       // 8KB
  __shared__ __align__(16) unsigned short wbuf[2][128 * 64];  // 32KB
  const int m = blockIdx.y;
  const int m0r = blockIdx.x * 64;
  const int t = threadIdx.x, lane = t & 63, w = t >> 6;
  const int l15 = lane & 15, l4 = lane >> 4;

  // async weight stages first (overlap with z conversion)
  {
    const unsigned short* g = wzzT + (size_t)m * 64 * 64;
    async16(g + t * 8, &wzz[t * 8]);
    async16(g + (t + 256) * 8, &wzz[(t + 256) * 8]);
    const unsigned short* gh = wzhT + (size_t)m * 512 * 64;  // chunk0: rows 0..127
#pragma unroll
    for (int it = 0; it < 4; ++it) {
      int id = it * 256 + t;
      async16(gh + id * 8, &wbuf[0][id * 8]);
    }
  }
  // z load + convert: 64 rows x 64 (s row stride = 80 floats, z at +16)
  const float* sb = s + ((size_t)m * BB + m0r) * (UU + ZD) + UU;
#pragma unroll
  for (int it = 0; it < 4; ++it) {
    int idx = it * 256 + t;  // 0..1023
    int row = idx >> 4, f4 = idx & 15;
    const float4 v = *(const float4*)(sb + (size_t)row * (UU + ZD) + f4 * 4);
    ushort4 h;
    h.x = f2bf(v.x); h.y = f2bf(v.y); h.z = f2bf(v.z); h.w = f2bf(v.w);
    *(ushort4*)&zA[row * 64 + f4 * 4] = h;
  }
  __syncthreads();

  // stage1: zz = z @ Wzz  (A: zA [64][64], wave w owns rows w*16..w*16+15)
  f32x4 acc1[4] = {};
#pragma unroll
  for (int ks = 0; ks < 2; ++ks) {
    short8 af, bf[4];
    af = *(const short8*)&zA[(w * 16 + l15) * 64 + ks * 32 + l4 * 8];
#pragma unroll
    for (int n = 0; n < 4; ++n)
      bf[n] = *(const short8*)&wzz[(n * 16 + l15) * 64 + ks * 32 + l4 * 8];
#pragma unroll
    for (int n = 0; n < 4; ++n) acc1[n] = MFMA16(af, bf[n], acc1[n]);
  }
  // issue wzh chunk1 while stage1 finishes
  {
    const unsigned short* gh = wzhT + (size_t)m * 512 * 64 + 128 * 64;
#pragma unroll
    for (int it = 0; it < 4; ++it) {
      int id = it * 256 + t;
      async16(gh + id * 8, &wbuf[1][id * 8]);
    }
  }
  __syncthreads();  // all zA reads done -> safe to overwrite with zz
  unsigned short* zzp = zA;
#pragma unroll
  for (int n = 0; n < 4; ++n)
#pragma unroll
    for (int r = 0; r < 4; ++r) {
      int row = w * 16 + l4 * 4 + r;
      int col = n * 16 + l15;
      zzp[row * 64 + col] = f2bf(acc1[n][r] + bzz[m * 64 + col]);
    }
  __syncthreads();  // zz ready; chunk1 drained too

  // stage2: h1 = relu(zz @ Wzh + bzh), 512 cols in 4 chunks of 128
  unsigned short* h1r = h1 + ((size_t)m * BB + m0r) * HH;
  for (int c = 0; c < 4; ++c) {
    f32x4 acc[8] = {};
#pragma unroll
    for (int ks = 0; ks < 2; ++ks) {
      short8 af, bf[8];
      af = *(const short8*)&zzp[(w * 16 + l15) * 64 + ks * 32 + l4 * 8];
#pragma unroll
      for (int n = 0; n < 8; ++n)
        bf[n] = *(const short8*)&wbuf[c & 1][(n * 16 + l15) * 64 + ks * 32 + l4 * 8];
#pragma unroll
      for (int n = 0; n < 8; ++n) acc[n] = MFMA16(af, bf[n], acc[n]);
    }
#pragma unroll
    for (int n = 0; n < 8; ++n)
#pragma unroll
      for (int r = 0; r < 4; ++r) {
        int row = w * 16 + l4 * 4 + r;
        int col = c * 128 + n * 16 + l15;
        float v = acc[n][r] + bzh[m * HH + col];
        h1r[(size_t)row * HH + col] = f2bf(fmaxf(v, 0.0f));
      }
    __syncthreads();  // everyone done reading wbuf[c&1]
    if (c + 2 < 4) {
      const unsigned short* gh = wzhT + (size_t)m * 512 * 64 + (size_t)(c + 2) * 128 * 64;
#pragma unroll
      for (int it = 0; it < 4; ++it) {
        int id = it * 256 + t;
        async16(gh + id * 8, &wbuf[c & 1][id * 8]);
      }
    }
  }
}

// ---------------- K2/K3: 128x128-tile bf16 GEMM, B^T layout ----------------
// 1D grid = MT*NTL blocks; T1 chunked XCD swizzle; N-tile innermost so each
// XCD keeps the whole B panel set L2-resident and streams each A panel once.
// EPI 0: relu -> bf16 out.  EPI 1: sigmoid -> f32 out.
template <int EPI, int Ntot, int Ktot, int MT, int NTL>
__global__ __launch_bounds__(256) void gemm_bt(
    const unsigned short* __restrict__ A,   // [MT*128][Ktot] bf16
    const unsigned short* __restrict__ BT,  // [Ntot][Ktot] bf16
    const float* __restrict__ bias,         // [Ntot]
    void* __restrict__ outp) {
  __shared__ __align__(16) unsigned short lA[2][128 * 32];  // 2x8KB
  __shared__ __align__(16) unsigned short lB[2][128 * 32];  // 2x8KB
  const int t = threadIdx.x, lane = t & 63;
  const int wid = t >> 6, wr = wid >> 1, wc = wid & 1;  // 2x2 waves, 64x64 each
  const int l15 = lane & 15, l4 = lane >> 4;

  // T1 swizzle (nwg % 8 == 0): XCD (bid&7) owns logical chunk [q*(bid&7), ...)
  constexpr int nwg = MT * NTL;
  constexpr int q = nwg / 8;
  const int bid = blockIdx.x;
  const int swz = (bid & 7) * q + (bid >> 3);
  const int mt = swz / NTL, nt = swz % NTL;
  const int m0 = mt * 128, n0 = nt * 128;

  const int ra = t >> 2;       // staging row (0..63); +64 for 2nd chunk
  const int sa = (t & 3) * 8;  // k-seg within 32 (elements)

  const unsigned short* gA = A + (size_t)m0 * Ktot;
  const unsigned short* gB = BT + (size_t)n0 * Ktot;

  float bv[4];
#pragma unroll
  for (int n = 0; n < 4; ++n) bv[n] = bias[n0 + wc * 64 + n * 16 + l15];

  f32x4 acc[4][4] = {};
  constexpr int KT = Ktot / 32;

  {  // prologue stage into buf 0
    const unsigned short* a0 = gA + (size_t)ra * Ktot + sa;
    const unsigned short* b0 = gB + (size_t)ra * Ktot + sa;
    async16(a0, &lA[0][t * 8]);
    async16(a0 + (size_t)64 * Ktot, &lA[0][(t + 256) * 8]);
    async16(b0, &lB[0][t * 8]);
    async16(b0 + (size_t)64 * Ktot, &lB[0][(t + 256) * 8]);
  }
  __syncthreads();
  for (int ks = 0; ks < KT; ++ks) {
    const int cur = ks & 1;
    if (ks + 1 < KT) {
      const int ko = (ks + 1) * 32;
      const unsigned short* a0 = gA + (size_t)ra * Ktot + ko + sa;
      const unsigned short* b0 = gB + (size_t)ra * Ktot + ko + sa;
      async16(a0, &lA[cur ^ 1][t * 8]);
      async16(a0 + (size_t)64 * Ktot, &lA[cur ^ 1][(t + 256) * 8]);
      async16(b0, &lB[cur ^ 1][t * 8]);
      async16(b0 + (size_t)64 * Ktot, &lB[cur ^ 1][(t + 256) * 8]);
    }
    short8 af[4], bf[4];
#pragma unroll
    for (int i = 0; i < 4; ++i)
      af[i] = *(const short8*)&lA[cur][(wr * 64 + i * 16 + l15) * 32 + l4 * 8];
#pragma unroll
    for (int n = 0; n < 4; ++n)
      bf[n] = *(const short8*)&lB[cur][(wc * 64 + n * 16 + l15) * 32 + l4 * 8];
#pragma unroll
    for (int i = 0; i < 4; ++i)
#pragma unroll
      for (int n = 0; n < 4; ++n) acc[i][n] = MFMA16(af[i], bf[n], acc[i][n]);
    __syncthreads();
  }

  // epilogue
#pragma unroll
  for (int i = 0; i < 4; ++i)
#pragma unroll
    for (int n = 0; n < 4; ++n) {
      const int col = n0 + wc * 64 + n * 16 + l15;
#pragma unroll
      for (int r = 0; r < 4; ++r) {
        const int row = m0 + wr * 64 + i * 16 + l4 * 4 + r;
        float v = acc[i][n][r] + bv[n];
        if (EPI == 0) {
          ((unsigned short*)outp)[(size_t)row * Ntot + col] = f2bf(fmaxf(v, 0.0f));
        } else {
          v = 1.0f / (1.0f + __expf(-v));
          ((float*)outp)[(size_t)row * Ntot + col] = v;
        }
      }
    }
}

extern "C" void kernel_launch(void* const* d_in, const int* in_sizes, int n_in,
                              void* d_out, int out_size, void* d_ws, size_t ws_size,
                              hipStream_t stream) {
  const float* s   = (const float*)d_in[0];
  const float* Wzz = (const float*)d_in[1];
  const float* bzz = (const float*)d_in[2];
  const float* Wzh = (const float*)d_in[3];
  const float* bzh = (const float*)d_in[4];
  const float* Whd = (const float*)d_in[5];
  const float* bhd = (const float*)d_in[6];
  const float* Whx = (const float*)d_in[7];
  const float* bhx = (const float*)d_in[8];
  float* out = (float*)d_out;

  char* ws = (char*)d_ws;
  unsigned short* wzzT = (unsigned short*)ws; ws += (size_t)MM * 64 * 64 * 2;
  unsigned short* wzhT = (unsigned short*)ws; ws += (size_t)MM * 512 * 64 * 2;
  unsigned short* whdT = (unsigned short*)ws; ws += (size_t)512 * 512 * 2;
  unsigned short* whxT = (unsigned short*)ws; ws += (size_t)3072 * 512 * 2;
  unsigned short* h1   = (unsigned short*)ws; ws += (size_t)RTOT * 512 * 2;
  unsigned short* h2   = (unsigned short*)ws;

  dim3 blk(256);
  trconv_all<<<dim3(2368), blk, 0, stream>>>(Wzz, Wzh, Whd, Whx, wzzT, wzhT, whdT, whxT);
  stage12<<<dim3(32, 16), blk, 0, stream>>>(s, wzzT, wzhT, bzz, bzh, h1);
  gemm_bt<0, HH, HH, 256, 4><<<dim3(1024), blk, 0, stream>>>(h1, whdT, bhd, (void*)h2);
  gemm_bt<1, XD, HH, 256, 24><<<dim3(6144), blk, 0, stream>>>(h2, whxT, bhx, (void*)out);
}

// Round 11
// 568.522 us; speedup vs baseline: 1.0413x; 1.0015x over previous
//
#include <hip/hip_runtime.h>
#include <stdint.h>

typedef __attribute__((ext_vector_type(4))) float f32x4;
typedef __attribute__((ext_vector_type(8))) short short8;

#define MM 16
#define BB 2048
#define UU 16
#define ZD 64
#define HH 512
#define XD 3072
#define RTOT (MM * BB)  // 32768

#define MFMA16(a, b, c) __builtin_amdgcn_mfma_f32_16x16x32_bf16(a, b, c, 0, 0, 0)

static __device__ __forceinline__ unsigned short f2bf(float f) {
  union { float f; uint32_t u; } v; v.f = f;
  uint32_t r = v.u + 0x7fffu + ((v.u >> 16) & 1u);
  return (unsigned short)(r >> 16);
}

static __device__ __forceinline__ void async16(const void* g, void* l) {
  __builtin_amdgcn_global_load_lds(
      (const __attribute__((address_space(1))) uint32_t*)g,
      (__attribute__((address_space(3))) uint32_t*)l, 16, 0, 0);
}

// ---------------- K0: transpose + fp32->bf16 convert, all 4 weights ----------------
static __device__ __forceinline__ void tr_tile(const float* __restrict__ in,
                                               unsigned short* __restrict__ out,
                                               int R, int C, int c0, int r0, int z,
                                               float (*tile)[33]) {
  const size_t base = (size_t)z * R * C;
  const int tx = threadIdx.x & 31, ty = threadIdx.x >> 5;  // 32x8
#pragma unroll
  for (int k = 0; k < 32; k += 8)
    tile[ty + k][tx] = in[base + (size_t)(r0 + ty + k) * C + c0 + tx];
  __syncthreads();
#pragma unroll
  for (int k = 0; k < 32; k += 8)
    out[base + (size_t)(c0 + ty + k) * R + r0 + tx] = f2bf(tile[tx][ty + k]);
}

// block ranges: [0,64) Wzz | [64,576) Wzh | [576,832) Whd | [832,2368) Whx
__global__ __launch_bounds__(256) void trconv_all(
    const float* __restrict__ Wzz, const float* __restrict__ Wzh,
    const float* __restrict__ Whd, const float* __restrict__ Whx,
    unsigned short* __restrict__ wzzT, unsigned short* __restrict__ wzhT,
    unsigned short* __restrict__ whdT, unsigned short* __restrict__ whxT) {
  __shared__ float tile[32][33];
  int b = blockIdx.x;
  if (b < 64) {
    int l = b;
    tr_tile(Wzz, wzzT, 64, 64, (l & 1) * 32, ((l >> 1) & 1) * 32, l >> 2, tile);
  } else if (b < 576) {
    int l = b - 64;
    tr_tile(Wzh, wzhT, 64, 512, (l & 15) * 32, ((l >> 4) & 1) * 32, l >> 5, tile);
  } else if (b < 832) {
    int l = b - 576;
    tr_tile(Whd, whdT, 512, 512, (l & 15) * 32, (l >> 4) * 32, 0, tile);
  } else {
    int l = b - 832;
    tr_tile(Whx, whxT, 512, 3072, (l % 96) * 32, (l / 96) * 32, 0, tile);
  }
}

// ---------------- K1: fused stage1+2 per m, 64 rows/block (512 blocks, 2/CU) ----------------
__global__ __launch_bounds__(256) void stage12(
    const float* __restrict__ s, const unsigned short* __restrict__ wzzT,
    const unsigned short* __restrict__ wzhT, const float* __restrict__ bzz,
    const float* __restrict__ bzh, unsigned short* __restrict__ h1) {
  __shared__ __align__(16) unsigned short zA[64 * 64];        // 8KB, reused as zz
  __shared__ __align__(16) unsigned short wzz[64 * 64];       // 8KB
  __shared__ __align__(16) unsigned short wbuf[2][128 * 64];  // 32KB
  const int m = blockIdx.y;
  const int m0r = blockIdx.x * 64;
  const int t = threadIdx.x, lane = t & 63, w = t >> 6;
  const int l15 = lane & 15, l4 = lane >> 4;

  // async weight stages first (overlap with z conversion)
  {
    const unsigned short* g = wzzT + (size_t)m * 64 * 64;
    async16(g + t * 8, &wzz[t * 8]);
    async16(g + (t + 256) * 8, &wzz[(t + 256) * 8]);
    const unsigned short* gh = wzhT + (size_t)m * 512 * 64;  // chunk0: rows 0..127
#pragma unroll
    for (int it = 0; it < 4; ++it) {
      int id = it * 256 + t;
      async16(gh + id * 8, &wbuf[0][id * 8]);
    }
  }
  // z load + convert: 64 rows x 64 (s row stride = 80 floats, z at +16)
  const float* sb = s + ((size_t)m * BB + m0r) * (UU + ZD) + UU;
#pragma unroll
  for (int it = 0; it < 4; ++it) {
    int idx = it * 256 + t;  // 0..1023
    int row = idx >> 4, f4 = idx & 15;
    const float4 v = *(const float4*)(sb + (size_t)row * (UU + ZD) + f4 * 4);
    ushort4 h;
    h.x = f2bf(v.x); h.y = f2bf(v.y); h.z = f2bf(v.z); h.w = f2bf(v.w);
    *(ushort4*)&zA[row * 64 + f4 * 4] = h;
  }
  __syncthreads();

  // stage1: zz = z @ Wzz  (A: zA [64][64], wave w owns rows w*16..w*16+15)
  f32x4 acc1[4] = {};
#pragma unroll
  for (int ks = 0; ks < 2; ++ks) {
    short8 af, bf[4];
    af = *(const short8*)&zA[(w * 16 + l15) * 64 + ks * 32 + l4 * 8];
#pragma unroll
    for (int n = 0; n < 4; ++n)
      bf[n] = *(const short8*)&wzz[(n * 16 + l15) * 64 + ks * 32 + l4 * 8];
#pragma unroll
    for (int n = 0; n < 4; ++n) acc1[n] = MFMA16(af, bf[n], acc1[n]);
  }
  // issue wzh chunk1 while stage1 finishes
  {
    const unsigned short* gh = wzhT + (size_t)m * 512 * 64 + 128 * 64;
#pragma unroll
    for (int it = 0; it < 4; ++it) {
      int id = it * 256 + t;
      async16(gh + id * 8, &wbuf[1][id * 8]);
    }
  }
  __syncthreads();  // all zA reads done -> safe to overwrite with zz
  unsigned short* zzp = zA;
#pragma unroll
  for (int n = 0; n < 4; ++n)
#pragma unroll
    for (int r = 0; r < 4; ++r) {
      int row = w * 16 + l4 * 4 + r;
      int col = n * 16 + l15;
      zzp[row * 64 + col] = f2bf(acc1[n][r] + bzz[m * 64 + col]);
    }
  __syncthreads();  // zz ready; chunk1 drained too

  // stage2: h1 = relu(zz @ Wzh + bzh), 512 cols in 4 chunks of 128
  unsigned short* h1r = h1 + ((size_t)m * BB + m0r) * HH;
  for (int c = 0; c < 4; ++c) {
    f32x4 acc[8] = {};
#pragma unroll
    for (int ks = 0; ks < 2; ++ks) {
      short8 af, bf[8];
      af = *(const short8*)&zzp[(w * 16 + l15) * 64 + ks * 32 + l4 * 8];
#pragma unroll
      for (int n = 0; n < 8; ++n)
        bf[n] = *(const short8*)&wbuf[c & 1][(n * 16 + l15) * 64 + ks * 32 + l4 * 8];
#pragma unroll
      for (int n = 0; n < 8; ++n) acc[n] = MFMA16(af, bf[n], acc[n]);
    }
#pragma unroll
    for (int n = 0; n < 8; ++n)
#pragma unroll
      for (int r = 0; r < 4; ++r) {
        int row = w * 16 + l4 * 4 + r;
        int col = c * 128 + n * 16 + l15;
        float v = acc[n][r] + bzh[m * HH + col];
        h1r[(size_t)row * HH + col] = f2bf(fmaxf(v, 0.0f));
      }
    __syncthreads();  // everyone done reading wbuf[c&1]
    if (c + 2 < 4) {
      const unsigned short* gh = wzhT + (size_t)m * 512 * 64 + (size_t)(c + 2) * 128 * 64;
#pragma unroll
      for (int it = 0; it < 4; ++it) {
        int id = it * 256 + t;
        async16(gh + id * 8, &wbuf[c & 1][id * 8]);
      }
    }
  }
}

// ---------------- K2/K3: 128x128-tile bf16 GEMM, B^T layout ----------------
// T4: 3-deep LDS ring, stage kt+2 during kt, counted vmcnt(4) + raw s_barrier
//     (never drain vmcnt to 0 in the main loop).
// T2: LDS slot-XOR swizzle: read slot = l4 ^ ((row>>1)&3); inverse applied on
//     the GLOBAL source (gload_lds dest must stay linear). 8-way -> 2-way.
// T1: chunked XCD swizzle, N-tile innermost.
// EPI 0: relu -> bf16 out.  EPI 1: sigmoid -> f32 out.
template <int EPI, int Ntot, int Ktot, int MT, int NTL>
__global__ __launch_bounds__(256) void gemm_bt(
    const unsigned short* __restrict__ A,   // [MT*128][Ktot] bf16
    const unsigned short* __restrict__ BT,  // [Ntot][Ktot] bf16
    const float* __restrict__ bias,         // [Ntot]
    void* __restrict__ outp) {
  __shared__ __align__(16) unsigned short lA[3][128 * 32];  // 3x8KB ring
  __shared__ __align__(16) unsigned short lB[3][128 * 32];  // 3x8KB ring
  const int t = threadIdx.x, lane = t & 63;
  const int wid = t >> 6, wr = wid >> 1, wc = wid & 1;  // 2x2 waves, 64x64 each
  const int l15 = lane & 15, l4 = lane >> 4;

  constexpr int nwg = MT * NTL;
  constexpr int q = nwg / 8;
  const int bid = blockIdx.x;
  const int swz = (bid & 7) * q + (bid >> 3);
  const int mt = swz / NTL, nt = swz % NTL;
  const int m0 = mt * 128, n0 = nt * 128;

  const int ra = t >> 2;  // staging row (0..63); +64 for 2nd chunk
  // T2 inverse-swizzle on global source: LDS[row][slot] gets G[row][slot^x(row)]
  const int sx = ((t & 3) ^ ((ra >> 1) & 3)) * 8;  // elems

  const unsigned short* pa = A + (size_t)(m0 + ra) * Ktot + sx;
  const unsigned short* pb = BT + (size_t)(n0 + ra) * Ktot + sx;

  float bv[4];
#pragma unroll
  for (int n = 0; n < 4; ++n) bv[n] = bias[n0 + wc * 64 + n * 16 + l15];

  // precomputed swizzled read offsets (elems within one 128x32 buffer)
  int aoff[4], boff[4];
#pragma unroll
  for (int i = 0; i < 4; ++i) {
    int row = wr * 64 + i * 16 + l15;
    aoff[i] = row * 32 + (l4 ^ ((row >> 1) & 3)) * 8;
    int col = wc * 64 + i * 16 + l15;
    boff[i] = col * 32 + (l4 ^ ((col >> 1) & 3)) * 8;
  }

  f32x4 acc[4][4] = {};
  constexpr int KT = Ktot / 32;

#define STAGE(bidx)                                     \
  do {                                                  \
    async16(pa, &lA[bidx][t * 8]);                      \
    async16(pa + (size_t)64 * Ktot, &lA[bidx][(t + 256) * 8]); \
    async16(pb, &lB[bidx][t * 8]);                      \
    async16(pb + (size_t)64 * Ktot, &lB[bidx][(t + 256) * 8]); \
    pa += 32; pb += 32;                                 \
  } while (0)

  // prologue: stage kt=0, kt=1; wait kt0 landed (4 of 8 outstanding), barrier
  STAGE(0);
  STAGE(1);
  asm volatile("s_waitcnt vmcnt(4)" ::: "memory");
  asm volatile("s_barrier" ::: "memory");

  int r3 = 0, s3 = 2;
  for (int kt = 0; kt < KT; ++kt) {
    if (kt + 2 < KT) STAGE(s3);  // prefetch kt+2 into free ring slot
    const unsigned short* la = lA[r3];
    const unsigned short* lb = lB[r3];
    short8 af[4], bf[4];
#pragma unroll
    for (int i = 0; i < 4; ++i) af[i] = *(const short8*)&la[aoff[i]];
#pragma unroll
    for (int n = 0; n < 4; ++n) bf[n] = *(const short8*)&lb[boff[n]];
#pragma unroll
    for (int i = 0; i < 4; ++i)
#pragma unroll
      for (int n = 0; n < 4; ++n) acc[i][n] = MFMA16(af[i], bf[n], acc[i][n]);
    if (kt + 1 < KT) {
      // kt+1's 4 loads must have landed; kt+2's (if issued) may stay in flight.
      // lgkmcnt(0): this iter's ds_reads retired before anyone re-stages r3.
      if (kt + 2 < KT)
        asm volatile("s_waitcnt vmcnt(4) lgkmcnt(0)" ::: "memory");
      else
        asm volatile("s_waitcnt vmcnt(0) lgkmcnt(0)" ::: "memory");
      asm volatile("s_barrier" ::: "memory");
    }
    r3 = (r3 == 2) ? 0 : r3 + 1;
    s3 = (s3 == 2) ? 0 : s3 + 1;
  }
#undef STAGE

  // epilogue
#pragma unroll
  for (int i = 0; i < 4; ++i)
#pragma unroll
    for (int n = 0; n < 4; ++n) {
      const int col = n0 + wc * 64 + n * 16 + l15;
#pragma unroll
      for (int r = 0; r < 4; ++r) {
        const int row = m0 + wr * 64 + i * 16 + l4 * 4 + r;
        float v = acc[i][n][r] + bv[n];
        if (EPI == 0) {
          ((unsigned short*)outp)[(size_t)row * Ntot + col] = f2bf(fmaxf(v, 0.0f));
        } else {
          v = 1.0f / (1.0f + __expf(-v));
          ((float*)outp)[(size_t)row * Ntot + col] = v;
        }
      }
    }
}

extern "C" void kernel_launch(void* const* d_in, const int* in_sizes, int n_in,
                              void* d_out, int out_size, void* d_ws, size_t ws_size,
                              hipStream_t stream) {
  const float* s   = (const float*)d_in[0];
  const float* Wzz = (const float*)d_in[1];
  const float* bzz = (const float*)d_in[2];
  const float* Wzh = (const float*)d_in[3];
  const float* bzh = (const float*)d_in[4];
  const float* Whd = (const float*)d_in[5];
  const float* bhd = (const float*)d_in[6];
  const float* Whx = (const float*)d_in[7];
  const float* bhx = (const float*)d_in[8];
  float* out = (float*)d_out;

  char* ws = (char*)d_ws;
  unsigned short* wzzT = (unsigned short*)ws; ws += (size_t)MM * 64 * 64 * 2;
  unsigned short* wzhT = (unsigned short*)ws; ws += (size_t)MM * 512 * 64 * 2;
  unsigned short* whdT = (unsigned short*)ws; ws += (size_t)512 * 512 * 2;
  unsigned short* whxT = (unsigned short*)ws; ws += (size_t)3072 * 512 * 2;
  unsigned short* h1   = (unsigned short*)ws; ws += (size_t)RTOT * 512 * 2;
  unsigned short* h2   = (unsigned short*)ws;

  dim3 blk(256);
  trconv_all<<<dim3(2368), blk, 0, stream>>>(Wzz, Wzh, Whd, Whx, wzzT, wzhT, whdT, whxT);
  stage12<<<dim3(32, 16), blk, 0, stream>>>(s, wzzT, wzhT, bzz, bzh, h1);
  gemm_bt<0, HH, HH, 256, 4><<<dim3(1024), blk, 0, stream>>>(h1, whdT, bhd, (void*)h2);
  gemm_bt<1, XD, HH, 256, 24><<<dim3(6144), blk, 0, stream>>>(h2, whxT, bhx, (void*)out);
}